// Round 12
// baseline (143.980 us; speedup 1.0000x reference)
//
#include <hip/hip_runtime.h>
#include <stdint.h>

#define M_DIM 8192   // K of the Gram GEMM
#define N_DIM 4096   // output N x N

typedef __attribute__((ext_vector_type(4))) int i32x4;
typedef __attribute__((ext_vector_type(8))) int i32x8;
typedef __attribute__((ext_vector_type(16))) float f32x16;

// fp32 -> OCP e4m3 (RNE, FTZ below 2^-6, saturate to 448)
__device__ __forceinline__ unsigned char f2e4m3(float x) {
  union { float f; uint32_t u; } v;
  v.f = x;
  const uint32_t s = (v.u >> 24) & 0x80;
  const uint32_t au = v.u & 0x7fffffffu;
  if (au < 0x3c800000u) return (unsigned char)s;  // |x| < 2^-6 -> 0
  const uint32_t r = au + 0x7ffffu + ((au >> 20) & 1u);  // RNE at 3 mantissa bits
  int e = (int)(r >> 23) - 127;
  uint32_t m = (r >> 20) & 7u;
  if (e > 8 || (e == 8 && m == 7)) { e = 8; m = 6; }  // sat 448, avoid NaN
  return (unsigned char)(s | ((uint32_t)(e + 7) << 3) | m);
}

__device__ __forceinline__ void gl_lds16b(const char* g, char* l) {
  __builtin_amdgcn_global_load_lds(
      (const __attribute__((address_space(1))) void*)g,
      (__attribute__((address_space(3))) void*)l, 16, 0, 0);
}

#define CFENCE asm volatile("" ::: "memory")

// ---------------- Kernel 1: A[M][N] fp32 -> At packed operand-major fp8.
// At layout: [nblk(16)][kc(128)][g(8)][c(4)][r32(32)][byte e(16)]
//   element (n, k): nblk=n>>8, kc=k>>6, g=(n>>5)&7, c=(k>>4)&3, r32=n&31, e=k&15
// 16KB per (nblk,kc); kc-major contiguity => a K=128 chunk is 32KB contiguous.
__global__ __launch_bounds__(256) void transpose_pack_fp8(
    const float* __restrict__ A, unsigned char* __restrict__ At) {
  __shared__ unsigned char tile[64][68];  // tile[x][y] = A[m0+y][n0+x]
  const int bm = blockIdx.x % (M_DIM / 64);
  const int bn = blockIdx.x / (M_DIM / 64);
  const int m0 = bm * 64, n0 = bn * 64;
  const int t = threadIdx.x;
  const int tr = t >> 4;
  const int tc = (t & 15) << 2;
#pragma unroll
  for (int p = 0; p < 4; ++p) {
    const int r = p * 16 + tr;  // m_local
    const float4 v = *reinterpret_cast<const float4*>(
        &A[(size_t)(m0 + r) * N_DIM + (n0 + tc)]);
    tile[tc + 0][r] = f2e4m3(v.x);
    tile[tc + 1][r] = f2e4m3(v.y);
    tile[tc + 2][r] = f2e4m3(v.z);
    tile[tc + 3][r] = f2e4m3(v.w);
  }
  __syncthreads();
  const int cC = (tc >> 4) & 3;   // k-chunk within 64
  const int eC = tc & 15;         // byte within 16B chunk
  const int nblk = n0 >> 8;
  const int kc = m0 >> 6;
  unsigned char* const obase = At + ((size_t)(nblk * 128 + kc) * 8) * 2048;
#pragma unroll
  for (int p = 0; p < 4; ++p) {
    const int rn = p * 16 + tr;       // n_local
    const int n = n0 + rn;
    const int g = (n >> 5) & 7;
    const int r32 = n & 31;
    uchar4 o;
    o.x = tile[rn][tc + 0];  // k = m0+tc+0 .. +3
    o.y = tile[rn][tc + 1];
    o.z = tile[rn][tc + 2];
    o.w = tile[rn][tc + 3];
    *reinterpret_cast<uchar4*>(
        &obase[g * 2048 + cC * 512 + r32 * 16 + eC]) = o;
  }
}

// ---------------- Kernel 2: 256x256 tile, 8 waves (2x4, wave 128x64),
// MX-scaled mfma_scale_f32_32x32x64_f8f6f4 (unit scales 0x7F = 2^0, exact).
// K=128 per iter (64 iters), 2 LDS bufs of 64KB (A 32KB @0, B 32KB @32768),
// stage chunk S+1 mid-iter, vmcnt(0)+barrier once per iter, no internal
// fences (compiler interleaves kk1 reads under kk0 MFMAs via lgkmcnt).
__global__ __launch_bounds__(512, 1) void gram_fp8s(
    const unsigned char* __restrict__ At, float* __restrict__ C) {
  __shared__ char smem[131072];

  const int bid = (int)blockIdx.x;
  const int wg = (bid & 7) * 32 + (bid >> 3);  // XCD swizzle (256 % 8 == 0)
  const int bi = wg >> 4, bj = wg & 15;

  const int t = (int)threadIdx.x;
  const int lane = t & 63, wave = t >> 6;
  const int wr = wave >> 2, wc = wave & 3;   // wave tile: rows wr*128, cols wc*64
  const int l31 = lane & 31, hi = lane >> 5;

  // operand read addresses within a 64KB buffer:
  //   A(kk half, block mb): kk*16384 + (wr*4+mb)*2048 + hi*1024 + l31*16 (+512)
  //   B(kk half, block nb): 32768 + kk*16384 + (wc*2+nb)*2048 + hi*1024 + l31*16
  int adA[2][4], adB[2][2];
#pragma unroll
  for (int kk = 0; kk < 2; ++kk) {
#pragma unroll
    for (int mb = 0; mb < 4; ++mb)
      adA[kk][mb] = kk * 16384 + (wr * 4 + mb) * 2048 + hi * 1024 + l31 * 16;
#pragma unroll
    for (int nb = 0; nb < 2; ++nb)
      adB[kk][nb] = 32768 + kk * 16384 + (wc * 2 + nb) * 2048 + hi * 1024 + l31 * 16;
  }

  // staging: plain linear 32KB copies per operand (packed layout == LDS layout)
  const char* const Atb = (const char*)At;
  const char* const sAc = Atb + (size_t)bi * (128 * 16384);
  const char* const sBc = Atb + (size_t)bj * (128 * 16384);
  const int dd = t * 16;  // 0..8176

  f32x16 acc[4][2] = {};

  // prologue: stage chunk 0 (K=128) into buf0: A 4 x 8KB, B 4 x 8KB
#pragma unroll
  for (int i = 0; i < 4; ++i) {
    gl_lds16b(sAc + i * 8192 + dd, smem + i * 8192 + dd);
    gl_lds16b(sBc + i * 8192 + dd, smem + 32768 + i * 8192 + dd);
  }

#define MFMA8(KK, AV, BV)                                                    \
  __builtin_amdgcn_s_setprio(1);                                             \
  _Pragma("unroll") for (int mb = 0; mb < 4; ++mb)                           \
    _Pragma("unroll") for (int nb = 0; nb < 2; ++nb)                         \
      acc[mb][nb] = __builtin_amdgcn_mfma_scale_f32_32x32x64_f8f6f4(         \
          AV[mb], BV[nb], acc[mb][nb], 0, 0, 0, 0x7F7F7F7F, 0, 0x7F7F7F7F);  \
  __builtin_amdgcn_s_setprio(0);

#define ITER(P, S, STG) do {                                                 \
  asm volatile("s_waitcnt vmcnt(0)" ::: "memory");                           \
  __builtin_amdgcn_s_barrier();                                              \
  CFENCE;                                                                    \
  {                                                                          \
    const char* const bb = smem + (P) * 65536;                               \
    char* const sbf = smem + (1 - (P)) * 65536;                              \
    const size_t ko = (size_t)((S) + 1) * 32768;                             \
    i32x8 av[4], bv[2];                                                      \
    /* kk = 0 reads */                                                       \
    _Pragma("unroll") for (int mb = 0; mb < 4; ++mb) {                       \
      const i32x4 lo = *reinterpret_cast<const i32x4*>(bb + adA[0][mb]);     \
      const i32x4 hv = *reinterpret_cast<const i32x4*>(bb + adA[0][mb] + 512);\
      av[mb] = __builtin_shufflevector(lo, hv, 0, 1, 2, 3, 4, 5, 6, 7);      \
    }                                                                        \
    _Pragma("unroll") for (int nb = 0; nb < 2; ++nb) {                       \
      const i32x4 lo = *reinterpret_cast<const i32x4*>(bb + adB[0][nb]);     \
      const i32x4 hv = *reinterpret_cast<const i32x4*>(bb + adB[0][nb] + 512);\
      bv[nb] = __builtin_shufflevector(lo, hv, 0, 1, 2, 3, 4, 5, 6, 7);      \
    }                                                                        \
    if (STG) {                                                               \
      gl_lds16b(sAc + ko + 0 * 8192 + dd, sbf + 0 * 8192 + dd);              \
      gl_lds16b(sAc + ko + 1 * 8192 + dd, sbf + 1 * 8192 + dd);              \
      gl_lds16b(sBc + ko + 0 * 8192 + dd, sbf + 32768 + 0 * 8192 + dd);      \
      gl_lds16b(sBc + ko + 1 * 8192 + dd, sbf + 32768 + 1 * 8192 + dd);      \
    }                                                                        \
    MFMA8(0, av, bv)                                                         \
    /* kk = 1 reads (overlap under kk0 MFMAs via compiler lgkmcnt) */        \
    _Pragma("unroll") for (int mb = 0; mb < 4; ++mb) {                       \
      const i32x4 lo = *reinterpret_cast<const i32x4*>(bb + adA[1][mb]);     \
      const i32x4 hv = *reinterpret_cast<const i32x4*>(bb + adA[1][mb] + 512);\
      av[mb] = __builtin_shufflevector(lo, hv, 0, 1, 2, 3, 4, 5, 6, 7);      \
    }                                                                        \
    _Pragma("unroll") for (int nb = 0; nb < 2; ++nb) {                       \
      const i32x4 lo = *reinterpret_cast<const i32x4*>(bb + adB[1][nb]);     \
      const i32x4 hv = *reinterpret_cast<const i32x4*>(bb + adB[1][nb] + 512);\
      bv[nb] = __builtin_shufflevector(lo, hv, 0, 1, 2, 3, 4, 5, 6, 7);      \
    }                                                                        \
    if (STG) {                                                               \
      gl_lds16b(sAc + ko + 2 * 8192 + dd, sbf + 2 * 8192 + dd);              \
      gl_lds16b(sAc + ko + 3 * 8192 + dd, sbf + 3 * 8192 + dd);              \
      gl_lds16b(sBc + ko + 2 * 8192 + dd, sbf + 32768 + 2 * 8192 + dd);      \
      gl_lds16b(sBc + ko + 3 * 8192 + dd, sbf + 32768 + 3 * 8192 + dd);      \
    }                                                                        \
    MFMA8(1, av, bv)                                                         \
  }                                                                          \
} while (0)

  // 64 K-chunks of 128; stage chunk S+1 in iters 0..62
  for (int s = 0; s < 62; s += 2) {
    ITER(0, s, true);
    ITER(1, s + 1, true);
  }
  ITER(0, 62, true);   // stages chunk 63
  ITER(1, 63, false);

#undef ITER
#undef MFMA8

  // epilogue: 32x32 C/D map (verified R6/R9/R11): col = lane&31,
  // row = (reg&3) + 8*(reg>>2) + 4*(lane>>5)
  const int rb = bi * 256 + wr * 128;
  const int cb = bj * 256 + wc * 64;
#pragma unroll
  for (int mb = 0; mb < 4; ++mb) {
#pragma unroll
    for (int nb = 0; nb < 2; ++nb) {
      const int c = cb + nb * 32 + l31;
#pragma unroll
      for (int rg = 0; rg < 4; ++rg) {
        const int r0 = rb + mb * 32 + rg * 8 + hi * 4;
#pragma unroll
        for (int j = 0; j < 4; ++j)
          C[(size_t)(r0 + j) * N_DIM + c] = acc[mb][nb][rg * 4 + j];
      }
    }
  }
}

extern "C" void kernel_launch(void* const* d_in, const int* in_sizes, int n_in,
                              void* d_out, int out_size, void* d_ws, size_t ws_size,
                              hipStream_t stream) {
  const float* A = (const float*)d_in[0];
  float* C = (float*)d_out;
  unsigned char* At = (unsigned char*)d_ws;  // 32 MiB packed

  transpose_pack_fp8<<<dim3((M_DIM / 64) * (N_DIM / 64)), 256, 0, stream>>>(A, At);
  gram_fp8s<<<dim3(16 * 16), 512, 0, stream>>>(At, C);
}

// Round 13
// 142.053 us; speedup vs baseline: 1.0136x; 1.0136x over previous
//
#include <hip/hip_runtime.h>
#include <stdint.h>

#define M_DIM 8192   // K of the Gram GEMM
#define N_DIM 4096   // output N x N

typedef __attribute__((ext_vector_type(4))) int i32x4;
typedef __attribute__((ext_vector_type(8))) int i32x8;
typedef __attribute__((ext_vector_type(16))) float f32x16;

// fp32 -> OCP e4m3 (RNE, FTZ below 2^-6, saturate to 448)
__device__ __forceinline__ unsigned char f2e4m3(float x) {
  union { float f; uint32_t u; } v;
  v.f = x;
  const uint32_t s = (v.u >> 24) & 0x80;
  const uint32_t au = v.u & 0x7fffffffu;
  if (au < 0x3c800000u) return (unsigned char)s;  // |x| < 2^-6 -> 0
  const uint32_t r = au + 0x7ffffu + ((au >> 20) & 1u);  // RNE at 3 mantissa bits
  int e = (int)(r >> 23) - 127;
  uint32_t m = (r >> 20) & 7u;
  if (e > 8 || (e == 8 && m == 7)) { e = 8; m = 6; }  // sat 448, avoid NaN
  return (unsigned char)(s | ((uint32_t)(e + 7) << 3) | m);
}

__device__ __forceinline__ void gl_lds16b(const char* g, char* l) {
  __builtin_amdgcn_global_load_lds(
      (const __attribute__((address_space(1))) void*)g,
      (__attribute__((address_space(3))) void*)l, 16, 0, 0);
}

#define CFENCE asm volatile("" ::: "memory")

// ---------------- Kernel 1: A[M][N] fp32 -> At packed operand-major fp8.
// At layout: [nblk(16)][kc(128)][g(8)][c(4)][r32(32)][byte e(16)]
//   element (n, k): nblk=n>>8, kc=k>>6, g=(n>>5)&7, c=(k>>4)&3, r32=n&31, e=k&15
// 16KB per (nblk,kc); kc-major contiguity => a K=128 chunk is 32KB contiguous.
__global__ __launch_bounds__(256) void transpose_pack_fp8(
    const float* __restrict__ A, unsigned char* __restrict__ At) {
  __shared__ unsigned char tile[64][68];  // tile[x][y] = A[m0+y][n0+x]
  const int bm = blockIdx.x % (M_DIM / 64);
  const int bn = blockIdx.x / (M_DIM / 64);
  const int m0 = bm * 64, n0 = bn * 64;
  const int t = threadIdx.x;
  const int tr = t >> 4;
  const int tc = (t & 15) << 2;
#pragma unroll
  for (int p = 0; p < 4; ++p) {
    const int r = p * 16 + tr;  // m_local
    const float4 v = *reinterpret_cast<const float4*>(
        &A[(size_t)(m0 + r) * N_DIM + (n0 + tc)]);
    tile[tc + 0][r] = f2e4m3(v.x);
    tile[tc + 1][r] = f2e4m3(v.y);
    tile[tc + 2][r] = f2e4m3(v.z);
    tile[tc + 3][r] = f2e4m3(v.w);
  }
  __syncthreads();
  const int cC = (tc >> 4) & 3;   // k-chunk within 64
  const int eC = tc & 15;         // byte within 16B chunk
  const int nblk = n0 >> 8;
  const int kc = m0 >> 6;
  unsigned char* const obase = At + ((size_t)(nblk * 128 + kc) * 8) * 2048;
#pragma unroll
  for (int p = 0; p < 4; ++p) {
    const int rn = p * 16 + tr;       // n_local
    const int n = n0 + rn;
    const int g = (n >> 5) & 7;
    const int r32 = n & 31;
    uchar4 o;
    o.x = tile[rn][tc + 0];  // k = m0+tc+0 .. +3
    o.y = tile[rn][tc + 1];
    o.z = tile[rn][tc + 2];
    o.w = tile[rn][tc + 3];
    *reinterpret_cast<uchar4*>(
        &obase[g * 2048 + cC * 512 + r32 * 16 + eC]) = o;
  }
}

// ---------------- Kernel 2: 256x256 tile, 8 waves (2x4, wave 128x64),
// MX-scaled mfma_scale_f32_32x32x64_f8f6f4 (unit scales 0x7F = 2^0, exact).
// K=128 per iter (64 iters), 2 LDS bufs of 64KB (A 32KB @0, B 32KB @32768),
// stage chunk S+1 mid-iter, vmcnt(0)+barrier once per iter, no internal
// fences (compiler interleaves kk1 reads under kk0 MFMAs via lgkmcnt).
__global__ __launch_bounds__(512, 1) void gram_fp8s(
    const unsigned char* __restrict__ At, float* __restrict__ C) {
  __shared__ char smem[131072];

  const int bid = (int)blockIdx.x;
  const int wg = (bid & 7) * 32 + (bid >> 3);  // XCD swizzle (256 % 8 == 0)
  const int bi = wg >> 4, bj = wg & 15;

  const int t = (int)threadIdx.x;
  const int lane = t & 63, wave = t >> 6;
  const int wr = wave >> 2, wc = wave & 3;   // wave tile: rows wr*128, cols wc*64
  const int l31 = lane & 31, hi = lane >> 5;

  // operand read addresses within a 64KB buffer:
  //   A(kk half, block mb): kk*16384 + (wr*4+mb)*2048 + hi*1024 + l31*16 (+512)
  //   B(kk half, block nb): 32768 + kk*16384 + (wc*2+nb)*2048 + hi*1024 + l31*16
  int adA[2][4], adB[2][2];
#pragma unroll
  for (int kk = 0; kk < 2; ++kk) {
#pragma unroll
    for (int mb = 0; mb < 4; ++mb)
      adA[kk][mb] = kk * 16384 + (wr * 4 + mb) * 2048 + hi * 1024 + l31 * 16;
#pragma unroll
    for (int nb = 0; nb < 2; ++nb)
      adB[kk][nb] = 32768 + kk * 16384 + (wc * 2 + nb) * 2048 + hi * 1024 + l31 * 16;
  }

  // staging: plain linear 32KB copies per operand (packed layout == LDS layout)
  const char* const Atb = (const char*)At;
  const char* const sAc = Atb + (size_t)bi * (128 * 16384);
  const char* const sBc = Atb + (size_t)bj * (128 * 16384);
  const int dd = t * 16;  // 0..8176

  f32x16 acc[4][2] = {};

  // prologue: stage chunk 0 (K=128) into buf0: A 4 x 8KB, B 4 x 8KB
#pragma unroll
  for (int i = 0; i < 4; ++i) {
    gl_lds16b(sAc + i * 8192 + dd, smem + i * 8192 + dd);
    gl_lds16b(sBc + i * 8192 + dd, smem + 32768 + i * 8192 + dd);
  }

#define MFMA8(KK, AV, BV)                                                    \
  __builtin_amdgcn_s_setprio(1);                                             \
  _Pragma("unroll") for (int mb = 0; mb < 4; ++mb)                           \
    _Pragma("unroll") for (int nb = 0; nb < 2; ++nb)                         \
      acc[mb][nb] = __builtin_amdgcn_mfma_scale_f32_32x32x64_f8f6f4(         \
          AV[mb], BV[nb], acc[mb][nb], 0, 0, 0, 0x7F7F7F7F, 0, 0x7F7F7F7F);  \
  __builtin_amdgcn_s_setprio(0);

#define ITER(P, S, STG) do {                                                 \
  asm volatile("s_waitcnt vmcnt(0)" ::: "memory");                           \
  __builtin_amdgcn_s_barrier();                                              \
  CFENCE;                                                                    \
  {                                                                          \
    const char* const bb = smem + (P) * 65536;                               \
    char* const sbf = smem + (1 - (P)) * 65536;                              \
    const size_t ko = (size_t)((S) + 1) * 32768;                             \
    i32x8 av[4], bv[2];                                                      \
    /* kk = 0 reads */                                                       \
    _Pragma("unroll") for (int mb = 0; mb < 4; ++mb) {                       \
      const i32x4 lo = *reinterpret_cast<const i32x4*>(bb + adA[0][mb]);     \
      const i32x4 hv = *reinterpret_cast<const i32x4*>(bb + adA[0][mb] + 512);\
      av[mb] = __builtin_shufflevector(lo, hv, 0, 1, 2, 3, 4, 5, 6, 7);      \
    }                                                                        \
    _Pragma("unroll") for (int nb = 0; nb < 2; ++nb) {                       \
      const i32x4 lo = *reinterpret_cast<const i32x4*>(bb + adB[0][nb]);     \
      const i32x4 hv = *reinterpret_cast<const i32x4*>(bb + adB[0][nb] + 512);\
      bv[nb] = __builtin_shufflevector(lo, hv, 0, 1, 2, 3, 4, 5, 6, 7);      \
    }                                                                        \
    if (STG) {                                                               \
      gl_lds16b(sAc + ko + 0 * 8192 + dd, sbf + 0 * 8192 + dd);              \
      gl_lds16b(sAc + ko + 1 * 8192 + dd, sbf + 1 * 8192 + dd);              \
      gl_lds16b(sBc + ko + 0 * 8192 + dd, sbf + 32768 + 0 * 8192 + dd);      \
      gl_lds16b(sBc + ko + 1 * 8192 + dd, sbf + 32768 + 1 * 8192 + dd);      \
    }                                                                        \
    MFMA8(0, av, bv)                                                         \
    /* kk = 1 reads (overlap under kk0 MFMAs via compiler lgkmcnt) */        \
    _Pragma("unroll") for (int mb = 0; mb < 4; ++mb) {                       \
      const i32x4 lo = *reinterpret_cast<const i32x4*>(bb + adA[1][mb]);     \
      const i32x4 hv = *reinterpret_cast<const i32x4*>(bb + adA[1][mb] + 512);\
      av[mb] = __builtin_shufflevector(lo, hv, 0, 1, 2, 3, 4, 5, 6, 7);      \
    }                                                                        \
    _Pragma("unroll") for (int nb = 0; nb < 2; ++nb) {                       \
      const i32x4 lo = *reinterpret_cast<const i32x4*>(bb + adB[1][nb]);     \
      const i32x4 hv = *reinterpret_cast<const i32x4*>(bb + adB[1][nb] + 512);\
      bv[nb] = __builtin_shufflevector(lo, hv, 0, 1, 2, 3, 4, 5, 6, 7);      \
    }                                                                        \
    if (STG) {                                                               \
      gl_lds16b(sAc + ko + 2 * 8192 + dd, sbf + 2 * 8192 + dd);              \
      gl_lds16b(sAc + ko + 3 * 8192 + dd, sbf + 3 * 8192 + dd);              \
      gl_lds16b(sBc + ko + 2 * 8192 + dd, sbf + 32768 + 2 * 8192 + dd);      \
      gl_lds16b(sBc + ko + 3 * 8192 + dd, sbf + 32768 + 3 * 8192 + dd);      \
    }                                                                        \
    MFMA8(1, av, bv)                                                         \
  }                                                                          \
} while (0)

  // 64 K-chunks of 128; stage chunk S+1 in iters 0..62
  for (int s = 0; s < 62; s += 2) {
    ITER(0, s, true);
    ITER(1, s + 1, true);
  }
  ITER(0, 62, true);   // stages chunk 63
  ITER(1, 63, false);

#undef ITER
#undef MFMA8

  // epilogue: 32x32 C/D map (verified R6/R9/R11): col = lane&31,
  // row = (reg&3) + 8*(reg>>2) + 4*(lane>>5)
  const int rb = bi * 256 + wr * 128;
  const int cb = bj * 256 + wc * 64;
#pragma unroll
  for (int mb = 0; mb < 4; ++mb) {
#pragma unroll
    for (int nb = 0; nb < 2; ++nb) {
      const int c = cb + nb * 32 + l31;
#pragma unroll
      for (int rg = 0; rg < 4; ++rg) {
        const int r0 = rb + mb * 32 + rg * 8 + hi * 4;
#pragma unroll
        for (int j = 0; j < 4; ++j)
          C[(size_t)(r0 + j) * N_DIM + c] = acc[mb][nb][rg * 4 + j];
      }
    }
  }
}

extern "C" void kernel_launch(void* const* d_in, const int* in_sizes, int n_in,
                              void* d_out, int out_size, void* d_ws, size_t ws_size,
                              hipStream_t stream) {
  const float* A = (const float*)d_in[0];
  float* C = (float*)d_out;
  unsigned char* At = (unsigned char*)d_ws;  // 32 MiB packed

  transpose_pack_fp8<<<dim3((M_DIM / 64) * (N_DIM / 64)), 256, 0, stream>>>(A, At);
  gram_fp8s<<<dim3(16 * 16), 512, 0, stream>>>(At, C);
}

// Round 14
// 138.560 us; speedup vs baseline: 1.0391x; 1.0252x over previous
//
#include <hip/hip_runtime.h>
#include <stdint.h>

#define M_DIM 8192   // K of the Gram GEMM
#define N_DIM 4096   // output N x N

typedef __attribute__((ext_vector_type(4))) int i32x4;
typedef __attribute__((ext_vector_type(8))) int i32x8;
typedef __attribute__((ext_vector_type(16))) float f32x16;

// fp32 -> OCP e4m3 (RNE, FTZ below 2^-6, saturate to 448)
__device__ __forceinline__ unsigned char f2e4m3(float x) {
  union { float f; uint32_t u; } v;
  v.f = x;
  const uint32_t s = (v.u >> 24) & 0x80;
  const uint32_t au = v.u & 0x7fffffffu;
  if (au < 0x3c800000u) return (unsigned char)s;  // |x| < 2^-6 -> 0
  const uint32_t r = au + 0x7ffffu + ((au >> 20) & 1u);  // RNE at 3 mantissa bits
  int e = (int)(r >> 23) - 127;
  uint32_t m = (r >> 20) & 7u;
  if (e > 8 || (e == 8 && m == 7)) { e = 8; m = 6; }  // sat 448, avoid NaN
  return (unsigned char)(s | ((uint32_t)(e + 7) << 3) | m);
}

__device__ __forceinline__ void gl_lds16b(const char* g, char* l) {
  __builtin_amdgcn_global_load_lds(
      (const __attribute__((address_space(1))) void*)g,
      (__attribute__((address_space(3))) void*)l, 16, 0, 0);
}

#define CFENCE asm volatile("" ::: "memory")

// ---------------- Kernel 1: A[M][N] fp32 -> At packed operand-major fp8.
// At layout: [nblk(16)][kc(128)][g(8)][c(4)][r32(32)][byte e(16)]
//   element (n, k): nblk=n>>8, kc=k>>6, g=(n>>5)&7, c=(k>>4)&3, r32=n&31, e=k&15
// 16KB per (nblk,kc) block; GEMM stages plain-linearly, reads operands as
// contiguous 512B regions (0-conflict class, verified R11).
__global__ __launch_bounds__(256) void transpose_pack_fp8(
    const float* __restrict__ A, unsigned char* __restrict__ At) {
  __shared__ unsigned char tile[64][68];  // tile[x][y] = A[m0+y][n0+x]
  const int bm = blockIdx.x % (M_DIM / 64);
  const int bn = blockIdx.x / (M_DIM / 64);
  const int m0 = bm * 64, n0 = bn * 64;
  const int t = threadIdx.x;
  const int tr = t >> 4;
  const int tc = (t & 15) << 2;
#pragma unroll
  for (int p = 0; p < 4; ++p) {
    const int r = p * 16 + tr;  // m_local
    const float4 v = *reinterpret_cast<const float4*>(
        &A[(size_t)(m0 + r) * N_DIM + (n0 + tc)]);
    tile[tc + 0][r] = f2e4m3(v.x);
    tile[tc + 1][r] = f2e4m3(v.y);
    tile[tc + 2][r] = f2e4m3(v.z);
    tile[tc + 3][r] = f2e4m3(v.w);
  }
  __syncthreads();
  const int cC = (tc >> 4) & 3;   // k-chunk within 64
  const int eC = tc & 15;         // byte within 16B chunk
  const int nblk = n0 >> 8;
  const int kc = m0 >> 6;
  unsigned char* const obase = At + ((size_t)(nblk * 128 + kc) * 8) * 2048;
#pragma unroll
  for (int p = 0; p < 4; ++p) {
    const int rn = p * 16 + tr;       // n_local
    const int n = n0 + rn;
    const int g = (n >> 5) & 7;
    const int r32 = n & 31;
    uchar4 o;
    o.x = tile[rn][tc + 0];  // k = m0+tc+0 .. +3
    o.y = tile[rn][tc + 1];
    o.z = tile[rn][tc + 2];
    o.w = tile[rn][tc + 3];
    *reinterpret_cast<uchar4*>(
        &obase[g * 2048 + cC * 512 + r32 * 16 + eC]) = o;
  }
}

// ---------------- Kernel 2: 256x256 tile, 4 waves (2x2, wave 128x128)
// -> LDS reads 64KB/iter (was 96). MX-scaled mfma_scale_f32_32x32x64_f8f6f4
// (unit scales). 4 bufs x 32KB, stage S+3, vmcnt(8)+barrier per iter,
// register double-buffered fragments: read chunk S+1's frags mid-iter S,
// interleaved per-mb with the MFMA stream. Packed layout: 0 conflicts.
__global__ __launch_bounds__(256, 1) void gram_fp8s(
    const unsigned char* __restrict__ At, float* __restrict__ C) {
  __shared__ char smem[131072];

  const int bid = (int)blockIdx.x;
  const int wg = (bid & 7) * 32 + (bid >> 3);  // XCD swizzle (256 % 8 == 0)
  const int bi = wg >> 4, bj = wg & 15;

  const int t = (int)threadIdx.x;
  const int lane = t & 63, wave = t >> 6;      // 4 waves
  const int wr = wave >> 1, wc = wave & 1;     // wave tile 128x128
  const int l31 = lane & 31, hi = lane >> 5;

  // operand read addresses: group block @ g*2048; chunks c = 2hi, 2hi+1
  int adA[4], adB[4];
#pragma unroll
  for (int mb = 0; mb < 4; ++mb)
    adA[mb] = (wr * 4 + mb) * 2048 + hi * 1024 + l31 * 16;
#pragma unroll
  for (int nb = 0; nb < 4; ++nb)
    adB[nb] = 16384 + (wc * 4 + nb) * 2048 + hi * 1024 + l31 * 16;

  // staging: plain linear 16KB copies; 256 threads x 16B = 4KB per gl_lds
  const char* const Atb = (const char*)At;
  const char* const sAc = Atb + (size_t)bi * (128 * 16384);
  const char* const sBc = Atb + (size_t)bj * (128 * 16384);
  const int dd = t * 16;  // 0..4080

  i32x8 fAv[2][4], fBv[2][4];
  f32x16 acc[4][4] = {};

  // prologue: stage chunks 0,1,2 into bufs 0,1,2 (8 gl_lds each)
#pragma unroll
  for (int ss = 0; ss < 3; ++ss) {
    char* const b = smem + ss * 32768;
    const size_t ko = (size_t)ss * 16384;
#pragma unroll
    for (int i = 0; i < 4; ++i) {
      gl_lds16b(sAc + ko + i * 4096 + dd, b + i * 4096 + dd);
      gl_lds16b(sBc + ko + i * 4096 + dd, b + 16384 + i * 4096 + dd);
    }
  }
  asm volatile("s_waitcnt vmcnt(16)" ::: "memory");
  __builtin_amdgcn_s_barrier();
  CFENCE;
  // read frags(0) into set 0
#pragma unroll
  for (int mb = 0; mb < 4; ++mb) {
    const i32x4 lo = *reinterpret_cast<const i32x4*>(smem + adA[mb]);
    const i32x4 hv = *reinterpret_cast<const i32x4*>(smem + adA[mb] + 512);
    fAv[0][mb] = __builtin_shufflevector(lo, hv, 0, 1, 2, 3, 4, 5, 6, 7);
  }
#pragma unroll
  for (int nb = 0; nb < 4; ++nb) {
    const i32x4 lo = *reinterpret_cast<const i32x4*>(smem + adB[nb]);
    const i32x4 hv = *reinterpret_cast<const i32x4*>(smem + adB[nb] + 512);
    fBv[0][nb] = __builtin_shufflevector(lo, hv, 0, 1, 2, 3, 4, 5, 6, 7);
  }

// iter S: MFMA with set CUR; read chunk S+1 frags into set NXT; stage S+3.
// Reads/stages interleaved per-mb group so the LDS port works under the
// matrix pipe.
#define ITER(S, CUR, NXT, STG, VMW, RDN) do {                                \
  if ((VMW) == 8)      asm volatile("s_waitcnt vmcnt(8)" ::: "memory");      \
  else if ((VMW) == 0) asm volatile("s_waitcnt vmcnt(0)" ::: "memory");      \
  __builtin_amdgcn_s_barrier();                                              \
  CFENCE;                                                                    \
  {                                                                          \
    const char* const bb = smem + (((S) + 1) & 3) * 32768;                   \
    char* const sbf = smem + (((S) + 3) & 3) * 32768;                        \
    const size_t ko = (size_t)((S) + 3) * 16384;                             \
    _Pragma("unroll") for (int mb = 0; mb < 4; ++mb) {                       \
      if (RDN) {                                                             \
        const i32x4 lo = *reinterpret_cast<const i32x4*>(bb + adA[mb]);      \
        const i32x4 hv = *reinterpret_cast<const i32x4*>(bb + adA[mb] + 512);\
        fAv[NXT][mb] = __builtin_shufflevector(lo, hv, 0, 1, 2, 3, 4, 5, 6, 7);\
      }                                                                      \
      if (STG)                                                               \
        gl_lds16b(sAc + ko + mb * 4096 + dd, sbf + mb * 4096 + dd);          \
      _Pragma("unroll") for (int nb = 0; nb < 4; ++nb)                       \
        acc[mb][nb] = __builtin_amdgcn_mfma_scale_f32_32x32x64_f8f6f4(       \
            fAv[CUR][mb], fBv[CUR][nb], acc[mb][nb], 0, 0,                   \
            0, 0x7F7F7F7F, 0, 0x7F7F7F7F);                                   \
      if (RDN) {                                                             \
        const i32x4 lo = *reinterpret_cast<const i32x4*>(bb + adB[mb]);      \
        const i32x4 hv = *reinterpret_cast<const i32x4*>(bb + adB[mb] + 512);\
        fBv[NXT][mb] = __builtin_shufflevector(lo, hv, 0, 1, 2, 3, 4, 5, 6, 7);\
      }                                                                      \
      if (STG)                                                               \
        gl_lds16b(sBc + ko + mb * 4096 + dd, sbf + 16384 + mb * 4096 + dd);  \
    }                                                                        \
  }                                                                          \
} while (0)

  // 128 K-chunks of 64; stage chunk S+3 in iters 0..124
  for (int s = 0; s < 124; s += 2) {
    ITER(s + 0, 0, 1, true, 8, 1);
    ITER(s + 1, 1, 0, true, 8, 1);
  }
  ITER(124, 0, 1, true, 8, 1);   // stages chunk 127, reads frags 125
  ITER(125, 1, 0, false, 8, 1);  // reads frags 126
  ITER(126, 0, 1, false, 0, 1);  // reads frags 127
  ITER(127, 1, 0, false, -1, 0); // MFMA only

#undef ITER

  // epilogue: 32x32 C/D map (verified R6/R9/R11): col = lane&31,
  // row = (reg&3) + 8*(reg>>2) + 4*(lane>>5)
  const int rb = bi * 256 + wr * 128;
  const int cb = bj * 256 + wc * 128;
#pragma unroll
  for (int mb = 0; mb < 4; ++mb) {
#pragma unroll
    for (int nb = 0; nb < 4; ++nb) {
      const int c = cb + nb * 32 + l31;
#pragma unroll
      for (int rg = 0; rg < 4; ++rg) {
        const int r0 = rb + mb * 32 + rg * 8 + hi * 4;
#pragma unroll
        for (int j = 0; j < 4; ++j)
          C[(size_t)(r0 + j) * N_DIM + c] = acc[mb][nb][rg * 4 + j];
      }
    }
  }
}

extern "C" void kernel_launch(void* const* d_in, const int* in_sizes, int n_in,
                              void* d_out, int out_size, void* d_ws, size_t ws_size,
                              hipStream_t stream) {
  const float* A = (const float*)d_in[0];
  float* C = (float*)d_out;
  unsigned char* At = (unsigned char*)d_ws;  // 32 MiB packed

  transpose_pack_fp8<<<dim3((M_DIM / 64) * (N_DIM / 64)), 256, 0, stream>>>(A, At);
  gram_fp8s<<<dim3(16 * 16), 256, 0, stream>>>(At, C);
}